// Round 1
// baseline (436.964 us; speedup 1.0000x reference)
//
#include <hip/hip_runtime.h>

// LengthRegulator: B=64, C=384, T=512 -> MAX_NEW_TIME=4096, dur in [0,8).
// Fused single-kernel version: each block computes the duration scan locally
// (2KB dur row) instead of a separate 64-block kernel + 26MB idx round-trip.

#define BB 64
#define CC 384
#define TT 512
#define TOUT 4096
#define CB 16   // channels per block: 16 rows x 2KB = 32KB LDS tile

// grid = (CC/CB, BB), block = 256.
// Phase 1 (LDS aliased into x-tile buffer): pair-sum Hillis-Steele scan of the
//   dur row, scatter frame index t into a 4096-entry idx table (-1 = zero tail),
//   read back 16 indices/thread into registers.
// Phase 2: write the register-staged x tile (loads issued at kernel start, HBM
//   latency hidden under phase 1) into LDS, then expand-gather with coalesced
//   float4 stores. Mask written by blockIdx.x==0 blocks from the c==0 row.
__global__ __launch_bounds__(256) void length_regulator_fused(
    const float* __restrict__ x, const int* __restrict__ dur,
    float* __restrict__ out, float* __restrict__ mask) {
  const int b = blockIdx.y;
  const int c0 = blockIdx.x * CB;
  const int tid = threadIdx.x;

  __shared__ float xs[CB * TT];            // 32 KB (phase 2)
  int* const idx_lds = (int*)xs;           // [TOUT]  16 KB (phase 1)
  int* const spair   = (int*)xs + TOUT;    // [256]    1 KB (phase 1)

  // Issue x-tile loads immediately (16B/lane, coalesced); consumed in phase 2.
  const float4* __restrict__ xb4 =
      (const float4*)(x + ((size_t)b * CC + c0) * TT);
  float4 xr[CB * TT / 4 / 256];            // 8 x float4 = 32 VGPRs
  #pragma unroll
  for (int k = 0; k < CB * TT / 4 / 256; ++k)
    xr[k] = xb4[k * 256 + tid];

  // ---- phase 1: scan + scatter ----
  const int2 d2 = ((const int2*)(dur + (size_t)b * TT))[tid];  // elems 2t,2t+1
  spair[tid] = d2.x + d2.y;
  #pragma unroll
  for (int k = 0; k < TOUT / 256; ++k) idx_lds[k * 256 + tid] = -1;
  __syncthreads();

  #pragma unroll
  for (int off = 1; off < 256; off <<= 1) {
    const int v = (tid >= off) ? spair[tid - off] : 0;
    __syncthreads();
    spair[tid] += v;
    __syncthreads();
  }

  const int e1 = spair[tid];      // inclusive csum at element 2*tid+1
  const int s1 = e1 - d2.y;       // = csum[2*tid] = start of element 2*tid+1
  const int s0 = s1 - d2.x;       // start of element 2*tid
  // total <= 512*7 = 3584 < 4096: scatter always in bounds; tail stays -1.
  for (int p = s0; p < s1; ++p) idx_lds[p] = 2 * tid;
  for (int p = s1; p < e1; ++p) idx_lds[p] = 2 * tid + 1;
  __syncthreads();

  int4 I[TOUT / 1024];
  #pragma unroll
  for (int jt = 0; jt < TOUT / 1024; ++jt)
    I[jt] = ((const int4*)idx_lds)[jt * 256 + tid];
  __syncthreads();   // all idx reads done before xs overwrites the table

  // ---- phase 2: stage x tile, then gather ----
  float4* const xs4 = (float4*)xs;
  #pragma unroll
  for (int k = 0; k < CB * TT / 4 / 256; ++k)
    xs4[k * 256 + tid] = xr[k];
  __syncthreads();

  float* __restrict__ ob = out + ((size_t)b * CC + c0) * TOUT + tid * 4;

  #pragma unroll
  for (int jt = 0; jt < TOUT / 1024; ++jt) {
    const int4 i4 = I[jt];   // compares + gather addresses hoisted across c
    #pragma unroll
    for (int c = 0; c < CB; ++c) {
      const float* __restrict__ row = xs + c * TT;
      float4 v;
      v.x = (i4.x >= 0) ? row[i4.x] : 0.0f;
      v.y = (i4.y >= 0) ? row[i4.y] : 0.0f;
      v.z = (i4.z >= 0) ? row[i4.z] : 0.0f;
      v.w = (i4.w >= 0) ? row[i4.w] : 0.0f;
      *(float4*)(ob + (size_t)c * TOUT + jt * 1024) = v;

      if (c == 0 && c0 == 0) {
        float4 m;
        m.x = (v.x != 0.0f) ? 1.0f : 0.0f;
        m.y = (v.y != 0.0f) ? 1.0f : 0.0f;
        m.z = (v.z != 0.0f) ? 1.0f : 0.0f;
        m.w = (v.w != 0.0f) ? 1.0f : 0.0f;
        *(float4*)(mask + (size_t)b * TOUT + jt * 1024 + tid * 4) = m;
      }
    }
  }
}

extern "C" void kernel_launch(void* const* d_in, const int* in_sizes, int n_in,
                              void* d_out, int out_size, void* d_ws, size_t ws_size,
                              hipStream_t stream) {
  const float* x = (const float*)d_in[0];       // (B, C, T) f32
  const int* dur = (const int*)d_in[1];         // (B, 1, T) i32

  float* out = (float*)d_out;                   // (B, C, TOUT) f32
  float* mask = out + (size_t)BB * CC * TOUT;   // (B, 1, TOUT)

  length_regulator_fused<<<dim3(CC / CB, BB), 256, 0, stream>>>(x, dur, out, mask);
}

// Round 3
// 432.114 us; speedup vs baseline: 1.0112x; 1.0112x over previous
//
#include <hip/hip_runtime.h>

// LengthRegulator: B=64, C=384, T=512 -> MAX_NEW_TIME=4096, dur in [0,8).
// v3b: CB=8 (16KB LDS tile, idx table aliased EXACTLY onto it -> ~8 blocks/CU
// vs 5), shfl-based wave scan (2 barriers vs 16), nontemporal float4 stores
// (out is write-once, never re-read: skip L2 allocation against the x reads).
// Fix vs v3: nontemporal builtin needs a NATIVE vector type, not HIP float4.

#define BB 64
#define CC 384
#define TT 512
#define TOUT 4096
#define CB 8    // channels per block: 8 rows x 2KB = 16KB LDS tile

typedef float f32x4 __attribute__((ext_vector_type(4)));

// grid = (CC/CB, BB) = (48, 64), block = 256 (4 waves).
__global__ __launch_bounds__(256) void length_regulator_v3(
    const float* __restrict__ x, const int* __restrict__ dur,
    float* __restrict__ out, float* __restrict__ mask) {
  const int b = blockIdx.y;
  const int c0 = blockIdx.x * CB;
  const int tid = threadIdx.x;
  const int lane = tid & 63;
  const int w = tid >> 6;

  __shared__ float xs[CB * TT];        // 16 KB x-tile (phase 2)
  __shared__ int wsum[4];              // wave totals for scan combine
  int* const idx_lds = (int*)xs;       // 4096 ints = 16 KB, exact alias (phase 1)

  // T14 async-stage: issue x-tile loads now (coalesced float4); HBM latency
  // hides under the scan. Consumed in phase 2.
  const f32x4* __restrict__ xb4 =
      (const f32x4*)(x + ((size_t)b * CC + c0) * TT);
  f32x4 xr[CB * TT / 4 / 256];         // 4 x float4 = 16 VGPRs
  #pragma unroll
  for (int k = 0; k < CB * TT / 4 / 256; ++k)
    xr[k] = xb4[k * 256 + tid];

  // ---- phase 1: duration scan (shfl) + scatter into idx table ----
  const int2 d2 = ((const int2*)(dur + (size_t)b * TT))[tid];  // elems 2t,2t+1
  int ps = d2.x + d2.y;
  #pragma unroll
  for (int off = 1; off < 64; off <<= 1) {
    const int v = __shfl_up(ps, off);
    if (lane >= off) ps += v;
  }

  // Fill idx with -1 (zero tail) while the scan's shuffles retire.
  #pragma unroll
  for (int k = 0; k < TOUT / 256; ++k) idx_lds[k * 256 + tid] = -1;
  if (lane == 63) wsum[w] = ps;
  __syncthreads();

  int prefix = 0;
  if (w > 0) prefix += wsum[0];
  if (w > 1) prefix += wsum[1];
  if (w > 2) prefix += wsum[2];
  const int e1 = ps + prefix;     // inclusive csum at element 2*tid+1
  const int s1 = e1 - d2.y;       // csum[2*tid] = start of element 2*tid+1
  const int s0 = s1 - d2.x;       // start of element 2*tid
  // total <= 512*7 = 3584 < 4096: always in bounds; tail stays -1.
  for (int p = s0; p < s1; ++p) idx_lds[p] = 2 * tid;
  for (int p = s1; p < e1; ++p) idx_lds[p] = 2 * tid + 1;
  __syncthreads();

  // This thread's 16 output indices (4 per j-tile of 1024), then free the LDS.
  int4 I[TOUT / 1024];
  #pragma unroll
  for (int jt = 0; jt < TOUT / 1024; ++jt)
    I[jt] = ((const int4*)idx_lds)[jt * 256 + tid];
  __syncthreads();

  // ---- phase 2: stage x tile, gather, streaming stores ----
  f32x4* const xs4 = (f32x4*)xs;
  #pragma unroll
  for (int k = 0; k < CB * TT / 4 / 256; ++k)
    xs4[k * 256 + tid] = xr[k];
  __syncthreads();

  float* __restrict__ ob = out + ((size_t)b * CC + c0) * TOUT + tid * 4;

  #pragma unroll
  for (int jt = 0; jt < TOUT / 1024; ++jt) {
    const int4 i4 = I[jt];
    #pragma unroll
    for (int c = 0; c < CB; ++c) {
      const float* __restrict__ row = xs + c * TT;
      f32x4 v;
      v.x = (i4.x >= 0) ? row[i4.x] : 0.0f;
      v.y = (i4.y >= 0) ? row[i4.y] : 0.0f;
      v.z = (i4.z >= 0) ? row[i4.z] : 0.0f;
      v.w = (i4.w >= 0) ? row[i4.w] : 0.0f;
      __builtin_nontemporal_store(
          v, (f32x4*)(ob + (size_t)c * TOUT + jt * 1024));

      if (c == 0 && c0 == 0) {
        f32x4 m;
        m.x = (v.x != 0.0f) ? 1.0f : 0.0f;
        m.y = (v.y != 0.0f) ? 1.0f : 0.0f;
        m.z = (v.z != 0.0f) ? 1.0f : 0.0f;
        m.w = (v.w != 0.0f) ? 1.0f : 0.0f;
        __builtin_nontemporal_store(
            m, (f32x4*)(mask + (size_t)b * TOUT + jt * 1024 + tid * 4));
      }
    }
  }
}

extern "C" void kernel_launch(void* const* d_in, const int* in_sizes, int n_in,
                              void* d_out, int out_size, void* d_ws, size_t ws_size,
                              hipStream_t stream) {
  const float* x = (const float*)d_in[0];       // (B, C, T) f32
  const int* dur = (const int*)d_in[1];         // (B, 1, T) i32

  float* out = (float*)d_out;                   // (B, C, TOUT) f32
  float* mask = out + (size_t)BB * CC * TOUT;   // (B, 1, TOUT)

  length_regulator_v3<<<dim3(CC / CB, BB), 256, 0, stream>>>(x, dur, out, mask);
}